// Round 1
// 95.231 us; speedup vs baseline: 1.0283x; 1.0283x over previous
//
#include <hip/hip_runtime.h>
#include <hip/hip_bf16.h>

typedef __attribute__((ext_vector_type(8))) short bf16x8;
typedef __attribute__((ext_vector_type(8))) int i32x8;
typedef __attribute__((ext_vector_type(4))) float f32x4;
typedef unsigned int uint;
typedef unsigned short u16;

#define NROWS 8192
#define F_DIM 128
#define Q_DIM 64
#define K1    192   // MFMA K for layer 1 (x + q only); graph col done in fp32
#define H_DIM 256
#define APITCH 200  // LDS row pitch for A (192 + 8 pad -> 4-bank row skew, 2-way max)

static __device__ inline unsigned short bf_bits(__hip_bfloat16 b) {
  unsigned short u; __builtin_memcpy(&u, &b, 2); return u;
}
static __device__ inline uint packhl(float v) {
  __hip_bfloat16 h = __float2bfloat16(v);
  float hf = __bfloat162float(h);
  __hip_bfloat16 l = __float2bfloat16(v - hf);
  return ((uint)bf_bits(l) << 16) | (uint)bf_bits(h);
}
static __device__ inline void split_hl(float v, unsigned short& h, unsigned short& l) {
  __hip_bfloat16 hb = __float2bfloat16(v);
  float hf = __bfloat162float(hb);
  __hip_bfloat16 lb = __float2bfloat16(v - hf);
  h = bf_bits(hb); l = bf_bits(lb);
}

union uu { uint4 u; bf16x8 v; };

// ---- prep: row norm -> xn8(fp8 e4m3), zero cnt, weight split into hi/lo planes
// 2048 blocks: each does 4 rows; blocks 0..255 also split W2 row bid,
// blocks 256..511 also split W1 row bid-256 (cols 0..191) + extract col 192;
// blocks 0..31 zero cnt.
__global__ __launch_bounds__(256) void norm_prep_kernel(const float* __restrict__ x,
                                                        const float* __restrict__ W1,
                                                        const float* __restrict__ W2,
                                                        unsigned char* __restrict__ xn8,
                                                        u16* __restrict__ W1h, u16* __restrict__ W1l,
                                                        u16* __restrict__ W2h, u16* __restrict__ W2l,
                                                        float* __restrict__ W1g,
                                                        int* __restrict__ cnt) {
  int tid = threadIdx.x;
  int bid = blockIdx.x;
  if (bid < 256) {
    u16 h, l; split_hl(W2[bid * 256 + tid], h, l);
    W2h[bid * 256 + tid] = h;
    W2l[bid * 256 + tid] = l;
  } else if (bid < 512) {
    int n = bid - 256;
    if (tid < K1) {
      u16 h, l; split_hl(W1[n * 193 + tid], h, l);
      W1h[n * K1 + tid] = h;
      W1l[n * K1 + tid] = l;
    } else if (tid == K1) {
      W1g[n] = W1[n * 193 + 192];  // graph-feature column, kept fp32
    }
  }
  if (bid < 32) cnt[bid * 256 + tid] = 0;

  int lane = tid & 63;
  int row = bid * 4 + (tid >> 6);
  const float2 v = *(const float2*)(x + (size_t)row * F_DIM + lane * 2);
  float s = v.x * v.x + v.y * v.y;
#pragma unroll
  for (int off = 32; off; off >>= 1) s += __shfl_xor(s, off);
  float inv = 1.0f / (sqrtf(s) + 1e-12f);
  int pk = __builtin_amdgcn_cvt_pk_fp8_f32(v.x * inv, v.y * inv, 0, 0);
  *(unsigned short*)(xn8 + (size_t)row * F_DIM + lane * 2) = (unsigned short)(pk & 0xffff);
}

// ---- Gram via MX-fp8 K=128 MFMA + threshold + row-count (unchanged) -------
__global__ __launch_bounds__(256) void gram8_kernel(const unsigned char* __restrict__ xn8,
                                                    int* __restrict__ cnt) {
  __shared__ char smem[32768];  // A 16KB + B 16KB; 128B rows, chunk ^ (row&7) swizzle
  int tid = threadIdx.x;
  int lane = tid & 63;
  int wave = tid >> 6;
  int lr = lane & 15;
  int quad = lane >> 4;

  int t = blockIdx.x;
  int bi = (int)((129.0f - sqrtf(129.0f * 129.0f - 8.0f * (float)t)) * 0.5f);
  while ((bi + 1) * (129 - (bi + 1)) / 2 <= t) bi++;
  while (bi * (129 - bi) / 2 > t) bi--;
  int bj = bi + (t - bi * (129 - bi) / 2);
  int i0 = bi * 128, j0 = bj * 128;

#pragma unroll
  for (int it = 0; it < 8; ++it) {
    int half = it >> 2;                    // 0 = A rows (i0), 1 = B rows (j0)
    int row = (it & 3) * 32 + (tid >> 3);
    int chunk = tid & 7;
    int grow = (half ? j0 : i0) + row;
    uint4 v = *(const uint4*)(xn8 + (size_t)grow * F_DIM + chunk * 16);
    *(uint4*)(smem + half * 16384 + row * 128 + ((chunk ^ (row & 7)) << 4)) = v;
  }
  __syncthreads();

  int wi = (wave >> 1) * 64, wj = (wave & 1) * 64;

  f32x4 acc[4][4];
#pragma unroll
  for (int i = 0; i < 4; i++)
#pragma unroll
    for (int j = 0; j < 4; j++) acc[i][j] = (f32x4){0.f, 0.f, 0.f, 0.f};

  i32x8 a[4], b[4];
#pragma unroll
  for (int tt = 0; tt < 4; tt++) {
    int r = wi + tt * 16 + lr;
    const char* base = smem + r * 128;
    uint4 lo = *(const uint4*)(base + (((2 * quad) ^ (r & 7)) << 4));
    uint4 hi = *(const uint4*)(base + (((2 * quad + 1) ^ (r & 7)) << 4));
    i32x8 f;
    f[0] = lo.x; f[1] = lo.y; f[2] = lo.z; f[3] = lo.w;
    f[4] = hi.x; f[5] = hi.y; f[6] = hi.z; f[7] = hi.w;
    a[tt] = f;
  }
#pragma unroll
  for (int tt = 0; tt < 4; tt++) {
    int r = wj + tt * 16 + lr;
    const char* base = smem + 16384 + r * 128;
    uint4 lo = *(const uint4*)(base + (((2 * quad) ^ (r & 7)) << 4));
    uint4 hi = *(const uint4*)(base + (((2 * quad + 1) ^ (r & 7)) << 4));
    i32x8 f;
    f[0] = lo.x; f[1] = lo.y; f[2] = lo.z; f[3] = lo.w;
    f[4] = hi.x; f[5] = hi.y; f[6] = hi.z; f[7] = hi.w;
    b[tt] = f;
  }

#pragma unroll
  for (int tr = 0; tr < 4; tr++)
#pragma unroll
    for (int tc = 0; tc < 4; tc++)
      acc[tr][tc] = __builtin_amdgcn_mfma_scale_f32_16x16x128_f8f6f4(
          a[tr], b[tc], acc[tr][tc], 0, 0, 0, 0x7f7f7f7f, 0, 0x7f7f7f7f);

  int i_base = i0 + wi, j_base = j0 + wj;
  bool diag_wave = (i_base == j_base);
  bool offdiag_block = (bi != bj);

  float mx = 0.f;
#pragma unroll
  for (int tr = 0; tr < 4; tr++)
#pragma unroll
    for (int tc = 0; tc < 4; tc++)
#pragma unroll
      for (int r = 0; r < 4; r++) {
        float v = acc[tr][tc][r];
        if (diag_wave && tr == tc && lr == quad * 4 + r) v = 0.f;
        mx = fmaxf(mx, fabsf(v));
      }
  if (__any(mx >= 0.9746f)) {
    for (int tr = 0; tr < 4; tr++)
      for (int tc = 0; tc < 4; tc++)
        for (int r = 0; r < 4; r++) {
          float v = acc[tr][tc][r];
          int row = i_base + tr * 16 + quad * 4 + r;
          int col = j_base + tc * 16 + lr;
          if (v * v >= 0.95f && row != col) {
            atomicAdd(&cnt[row], 1);
            if (offdiag_block) atomicAdd(&cnt[col], 1);
          }
        }
  }
}

// ---- fused MLP: 32 rows/block, barrier-free k-loops ----------------------
// A (x,q hi/lo) staged once in LDS; B fragments load DIRECTLY global->VGPR
// from pre-split W planes (each B element consumed exactly once -> no LDS).
// Graph column applied as exact fp32 rank-1 update after phase 1.
// LDS: Ahs [32][200] (12800B) | Als [32][200] (12800B) | H1 packed [32][256]
// uints (32768B) = 58368B. part[4][32] overlays Ahs at the end.
__global__ __launch_bounds__(256) void fused_mlp_kernel(const float* __restrict__ x,
                                                        const float* __restrict__ q,
                                                        const u16* __restrict__ W1h,
                                                        const u16* __restrict__ W1l,
                                                        const u16* __restrict__ W2h,
                                                        const u16* __restrict__ W2l,
                                                        const float* __restrict__ W1g,
                                                        const float* __restrict__ b1,
                                                        const float* __restrict__ b2,
                                                        const float* __restrict__ W3,
                                                        const float* __restrict__ b3,
                                                        const int* __restrict__ cnt,
                                                        float* __restrict__ out) {
  __shared__ __align__(16) char smem[58368];
  short* Ahs = (short*)smem;                 // [32][APITCH] hi
  short* Als = (short*)(smem + 12800);       // [32][APITCH] lo
  uint*  H1  = (uint*)(smem + 25600);        // [32][256] packed, swizzled
  float* part = (float*)smem;                // [4][32], overlays Ahs at end

  int tid = threadIdx.x;
  int lane = tid & 63;
  int wv = tid >> 6;
  int lr = lane & 15;
  int quad = lane >> 4;
  int mb = blockIdx.x * 32;

  // ---- A stage: feats[32][192] hi/lo from x, q ----
  {
    int r = tid >> 3;
    int c8 = (tid & 7) * 4;
#pragma unroll
    for (int it = 0; it < 6; ++it) {
      int col = it * 32 + c8;
      float4 v;
      if (it < 4) v = *(const float4*)(x + (size_t)(mb + r) * F_DIM + col);
      else        v = *(const float4*)(q + (size_t)(mb + r) * Q_DIM + (col - 128));
      unsigned short h0, l0, h1, l1, h2, l2, h3, l3;
      split_hl(v.x, h0, l0); split_hl(v.y, h1, l1);
      split_hl(v.z, h2, l2); split_hl(v.w, h3, l3);
      *(uint2*)&Ahs[r * APITCH + col] = (uint2){(uint)h0 | ((uint)h1 << 16), (uint)h2 | ((uint)h3 << 16)};
      *(uint2*)&Als[r * APITCH + col] = (uint2){(uint)l0 | ((uint)l1 << 16), (uint)l2 | ((uint)l3 << 16)};
    }
  }
  __syncthreads();

  f32x4 acc[2][4];
#pragma unroll
  for (int i = 0; i < 2; i++)
#pragma unroll
    for (int j = 0; j < 4; j++) acc[i][j] = (f32x4){0.f, 0.f, 0.f, 0.f};

  // ---- phase 1: h1_pre = feats @ W1^T, K = 192, no barriers ----
  for (int kc = 0; kc < 6; ++kc) {
    int k0 = kc * 32;
    bf16x8 ah[2], al[2], bh[4], bl[4];
#pragma unroll
    for (int tt = 0; tt < 2; ++tt) {
      int row = tt * 16 + lr;
      ah[tt] = *(const bf16x8*)&Ahs[row * APITCH + k0 + quad * 8];
      al[tt] = *(const bf16x8*)&Als[row * APITCH + k0 + quad * 8];
    }
#pragma unroll
    for (int tc = 0; tc < 4; ++tc) {
      int n = wv * 64 + tc * 16 + lr;
      bh[tc] = *(const bf16x8*)(W1h + (size_t)n * K1 + k0 + quad * 8);
      bl[tc] = *(const bf16x8*)(W1l + (size_t)n * K1 + k0 + quad * 8);
    }
#pragma unroll
    for (int tt = 0; tt < 2; ++tt)
#pragma unroll
      for (int tc = 0; tc < 4; ++tc) {
        acc[tt][tc] = __builtin_amdgcn_mfma_f32_16x16x32_bf16(ah[tt], bh[tc], acc[tt][tc], 0, 0, 0);
        acc[tt][tc] = __builtin_amdgcn_mfma_f32_16x16x32_bf16(ah[tt], bl[tc], acc[tt][tc], 0, 0, 0);
        acc[tt][tc] = __builtin_amdgcn_mfma_f32_16x16x32_bf16(al[tt], bh[tc], acc[tt][tc], 0, 0, 0);
      }
  }

  // ---- graph-feature column: exact fp32 rank-1 update ----
  {
    float gv[2][4];
#pragma unroll
    for (int tt = 0; tt < 2; ++tt)
#pragma unroll
      for (int r = 0; r < 4; ++r)
        gv[tt][r] = (float)cnt[mb + tt * 16 + quad * 4 + r] * (1.0f / 8192.0f);
#pragma unroll
    for (int tc = 0; tc < 4; ++tc) {
      int n = wv * 64 + tc * 16 + lr;
      float w = W1g[n];
#pragma unroll
      for (int tt = 0; tt < 2; ++tt)
#pragma unroll
        for (int r = 0; r < 4; ++r)
          acc[tt][tc][r] += gv[tt][r] * w;
    }
  }

  // ---- phase-1 epilogue: relu+bias -> H1 (packed, swizzled) ----
#pragma unroll
  for (int tc = 0; tc < 4; ++tc) {
    int n = wv * 64 + tc * 16 + lr;
    float bv = b1[n];
    int g = n >> 2, jj = n & 3;
#pragma unroll
    for (int tt = 0; tt < 2; ++tt)
#pragma unroll
      for (int r = 0; r < 4; ++r) {
        int row = tt * 16 + quad * 4 + r;
        float v = fmaxf(acc[tt][tc][r] + bv, 0.f);
        H1[row * 256 + ((g ^ (row & 31)) * 4 + jj)] = packhl(v);
      }
  }
#pragma unroll
  for (int i = 0; i < 2; i++)
#pragma unroll
    for (int j = 0; j < 4; j++) acc[i][j] = (f32x4){0.f, 0.f, 0.f, 0.f};
  __syncthreads();   // all H1 writes visible before phase 2 reads

  // ---- phase 2: h2 = relu(h1 @ W2^T + b2), K = 256, no barriers ----
  for (int kc = 0; kc < 8; ++kc) {
    bf16x8 ah[2], al[2], bh[4], bl[4];
#pragma unroll
    for (int tt = 0; tt < 2; ++tt) {
      int row = tt * 16 + lr;
      int cb = kc * 8 + quad * 2;
      uint4 u0 = *(const uint4*)&H1[row * 256 + ((cb ^ (row & 31)) * 4)];
      uint4 u1 = *(const uint4*)&H1[row * 256 + (((cb + 1) ^ (row & 31)) * 4)];
      uu h, l;
      h.u.x = (u0.x & 0xffffu) | (u0.y << 16);
      h.u.y = (u0.z & 0xffffu) | (u0.w << 16);
      h.u.z = (u1.x & 0xffffu) | (u1.y << 16);
      h.u.w = (u1.z & 0xffffu) | (u1.w << 16);
      l.u.x = (u0.x >> 16) | (u0.y & 0xffff0000u);
      l.u.y = (u0.z >> 16) | (u0.w & 0xffff0000u);
      l.u.z = (u1.x >> 16) | (u1.y & 0xffff0000u);
      l.u.w = (u1.z >> 16) | (u1.w & 0xffff0000u);
      ah[tt] = h.v; al[tt] = l.v;
    }
#pragma unroll
    for (int tc = 0; tc < 4; ++tc) {
      int n = wv * 64 + tc * 16 + lr;
      bh[tc] = *(const bf16x8*)(W2h + (size_t)n * 256 + kc * 32 + quad * 8);
      bl[tc] = *(const bf16x8*)(W2l + (size_t)n * 256 + kc * 32 + quad * 8);
    }
#pragma unroll
    for (int tt = 0; tt < 2; ++tt)
#pragma unroll
      for (int tc = 0; tc < 4; ++tc) {
        acc[tt][tc] = __builtin_amdgcn_mfma_f32_16x16x32_bf16(ah[tt], bh[tc], acc[tt][tc], 0, 0, 0);
        acc[tt][tc] = __builtin_amdgcn_mfma_f32_16x16x32_bf16(ah[tt], bl[tc], acc[tt][tc], 0, 0, 0);
        acc[tt][tc] = __builtin_amdgcn_mfma_f32_16x16x32_bf16(al[tt], bh[tc], acc[tt][tc], 0, 0, 0);
      }
  }

  // ---- phase-2 epilogue: relu+bias, dot W3, cross-wave reduce, store ----
  float s[2][4];
#pragma unroll
  for (int tt = 0; tt < 2; ++tt)
#pragma unroll
    for (int r = 0; r < 4; ++r) s[tt][r] = 0.f;
#pragma unroll
  for (int tc = 0; tc < 4; ++tc) {
    int n = wv * 64 + tc * 16 + lr;
    float bv = b2[n];
    float w3 = W3[n];
#pragma unroll
    for (int tt = 0; tt < 2; ++tt)
#pragma unroll
      for (int r = 0; r < 4; ++r)
        s[tt][r] += fmaxf(acc[tt][tc][r] + bv, 0.f) * w3;
  }
#pragma unroll
  for (int tt = 0; tt < 2; ++tt)
#pragma unroll
    for (int r = 0; r < 4; ++r) {
      s[tt][r] += __shfl_xor(s[tt][r], 1);
      s[tt][r] += __shfl_xor(s[tt][r], 2);
      s[tt][r] += __shfl_xor(s[tt][r], 4);
      s[tt][r] += __shfl_xor(s[tt][r], 8);
    }
  // part overlays Ahs: all A reads completed before the post-H1 barrier
  if (lr == 0) {
#pragma unroll
    for (int tt = 0; tt < 2; ++tt)
#pragma unroll
      for (int r = 0; r < 4; ++r)
        part[wv * 32 + tt * 16 + quad * 4 + r] = s[tt][r];
  }
  __syncthreads();
  if (tid < 32)
    out[mb + tid] = part[tid] + part[32 + tid] + part[64 + tid] + part[96 + tid] + b3[0];
}

extern "C" void kernel_launch(void* const* d_in, const int* in_sizes, int n_in,
                              void* d_out, int out_size, void* d_ws, size_t ws_size,
                              hipStream_t stream) {
  const float* x  = (const float*)d_in[0];
  const float* q  = (const float*)d_in[1];
  const float* W1 = (const float*)d_in[2];
  const float* b1 = (const float*)d_in[3];
  const float* W2 = (const float*)d_in[4];
  const float* b2 = (const float*)d_in[5];
  const float* W3 = (const float*)d_in[6];
  const float* b3 = (const float*)d_in[7];
  float* out = (float*)d_out;

  char* ws = (char*)d_ws;
  unsigned char* xn8 = (unsigned char*)(ws);         // 1 MB
  int*   cnt = (int*)(ws + 0x100000);                // 32 KB
  u16*   W1h = (u16*)(ws + 0x110000);                // 96 KB  (256 x 192)
  u16*   W1l = (u16*)(ws + 0x128000);                // 96 KB
  u16*   W2h = (u16*)(ws + 0x140000);                // 128 KB (256 x 256)
  u16*   W2l = (u16*)(ws + 0x160000);                // 128 KB
  float* W1g = (float*)(ws + 0x180000);              // 1 KB (W1 col 192, fp32)

  norm_prep_kernel<<<dim3(2048), dim3(256), 0, stream>>>(x, W1, W2, xn8, W1h, W1l, W2h, W2l, W1g, cnt);
  gram8_kernel<<<dim3(2080), dim3(256), 0, stream>>>(xn8, cnt);
  fused_mlp_kernel<<<dim3(256), dim3(256), 0, stream>>>(x, q, W1h, W1l, W2h, W2l, W1g, b1, b2, W3, b3, cnt, out);
}

// Round 2
// 94.195 us; speedup vs baseline: 1.0396x; 1.0110x over previous
//
#include <hip/hip_runtime.h>
#include <hip/hip_bf16.h>

typedef __attribute__((ext_vector_type(8))) short bf16x8;
typedef __attribute__((ext_vector_type(8))) int i32x8;
typedef __attribute__((ext_vector_type(4))) float f32x4;
typedef unsigned int uint;
typedef unsigned short u16;

#define NROWS 8192
#define F_DIM 128
#define Q_DIM 64
#define K1    192   // MFMA K for layer 1 (x + q only); graph col done in fp32
#define H_DIM 256
#define APITCH 200  // LDS row pitch for A (192 + 8 pad)

static __device__ inline unsigned short bf_bits(__hip_bfloat16 b) {
  unsigned short u; __builtin_memcpy(&u, &b, 2); return u;
}
static __device__ inline uint packhl(float v) {
  __hip_bfloat16 h = __float2bfloat16(v);
  float hf = __bfloat162float(h);
  __hip_bfloat16 l = __float2bfloat16(v - hf);
  return ((uint)bf_bits(l) << 16) | (uint)bf_bits(h);
}
static __device__ inline void split_hl(float v, unsigned short& h, unsigned short& l) {
  __hip_bfloat16 hb = __float2bfloat16(v);
  float hf = __bfloat162float(hb);
  __hip_bfloat16 lb = __float2bfloat16(v - hf);
  h = bf_bits(hb); l = bf_bits(lb);
}

union uu { uint4 u; bf16x8 v; };

// ---- prep: row norm -> xn8(fp8 e4m3), zero cnt ----------------------------
// 2048 blocks x 4 rows. Weight splitting moved into gram8's grid tail.
__global__ __launch_bounds__(256) void norm_prep_kernel(const float* __restrict__ x,
                                                        unsigned char* __restrict__ xn8,
                                                        int* __restrict__ cnt) {
  int tid = threadIdx.x;
  int bid = blockIdx.x;
  if (bid < 32) cnt[bid * 256 + tid] = 0;

  int lane = tid & 63;
  int row = bid * 4 + (tid >> 6);
  const float2 v = *(const float2*)(x + (size_t)row * F_DIM + lane * 2);
  float s = v.x * v.x + v.y * v.y;
#pragma unroll
  for (int off = 32; off; off >>= 1) s += __shfl_xor(s, off);
  float inv = 1.0f / (sqrtf(s) + 1e-12f);
  int pk = __builtin_amdgcn_cvt_pk_fp8_f32(v.x * inv, v.y * inv, 0, 0);
  *(unsigned short*)(xn8 + (size_t)row * F_DIM + lane * 2) = (unsigned short)(pk & 0xffff);
}

// ---- Gram via MX-fp8 K=128 MFMA + threshold + row-count -------------------
// blocks 0..2079: gram tiles.  blocks 2080..2591: weight hi/lo split
// (independent of xn8/cnt; fills the gram tail).
__global__ __launch_bounds__(256) void gram8_kernel(const unsigned char* __restrict__ xn8,
                                                    int* __restrict__ cnt,
                                                    const float* __restrict__ W1,
                                                    const float* __restrict__ W2,
                                                    u16* __restrict__ W1h, u16* __restrict__ W1l,
                                                    u16* __restrict__ W2h, u16* __restrict__ W2l,
                                                    float* __restrict__ W1g) {
  int tid = threadIdx.x;
  int t = blockIdx.x;
  if (t >= 2080) {
    int b = t - 2080;
    if (b < 256) {
      u16 h, l; split_hl(W2[b * 256 + tid], h, l);
      W2h[b * 256 + tid] = h;
      W2l[b * 256 + tid] = l;
    } else {
      int n = b - 256;
      if (tid < K1) {
        u16 h, l; split_hl(W1[n * 193 + tid], h, l);
        W1h[n * K1 + tid] = h;
        W1l[n * K1 + tid] = l;
      } else if (tid == K1) {
        W1g[n] = W1[n * 193 + 192];  // graph-feature column, kept fp32
      }
    }
    return;
  }

  __shared__ char smem[32768];  // A 16KB + B 16KB; 128B rows, chunk ^ (row&7) swizzle
  int lane = tid & 63;
  int wave = tid >> 6;
  int lr = lane & 15;
  int quad = lane >> 4;

  int bi = (int)((129.0f - sqrtf(129.0f * 129.0f - 8.0f * (float)t)) * 0.5f);
  while ((bi + 1) * (129 - (bi + 1)) / 2 <= t) bi++;
  while (bi * (129 - bi) / 2 > t) bi--;
  int bj = bi + (t - bi * (129 - bi) / 2);
  int i0 = bi * 128, j0 = bj * 128;

#pragma unroll
  for (int it = 0; it < 8; ++it) {
    int half = it >> 2;                    // 0 = A rows (i0), 1 = B rows (j0)
    int row = (it & 3) * 32 + (tid >> 3);
    int chunk = tid & 7;
    int grow = (half ? j0 : i0) + row;
    uint4 v = *(const uint4*)(xn8 + (size_t)grow * F_DIM + chunk * 16);
    *(uint4*)(smem + half * 16384 + row * 128 + ((chunk ^ (row & 7)) << 4)) = v;
  }
  __syncthreads();

  int wi = (wave >> 1) * 64, wj = (wave & 1) * 64;

  f32x4 acc[4][4];
#pragma unroll
  for (int i = 0; i < 4; i++)
#pragma unroll
    for (int j = 0; j < 4; j++) acc[i][j] = (f32x4){0.f, 0.f, 0.f, 0.f};

  i32x8 a[4], b[4];
#pragma unroll
  for (int tt = 0; tt < 4; tt++) {
    int r = wi + tt * 16 + lr;
    const char* base = smem + r * 128;
    uint4 lo = *(const uint4*)(base + (((2 * quad) ^ (r & 7)) << 4));
    uint4 hi = *(const uint4*)(base + (((2 * quad + 1) ^ (r & 7)) << 4));
    i32x8 f;
    f[0] = lo.x; f[1] = lo.y; f[2] = lo.z; f[3] = lo.w;
    f[4] = hi.x; f[5] = hi.y; f[6] = hi.z; f[7] = hi.w;
    a[tt] = f;
  }
#pragma unroll
  for (int tt = 0; tt < 4; tt++) {
    int r = wj + tt * 16 + lr;
    const char* base = smem + 16384 + r * 128;
    uint4 lo = *(const uint4*)(base + (((2 * quad) ^ (r & 7)) << 4));
    uint4 hi = *(const uint4*)(base + (((2 * quad + 1) ^ (r & 7)) << 4));
    i32x8 f;
    f[0] = lo.x; f[1] = lo.y; f[2] = lo.z; f[3] = lo.w;
    f[4] = hi.x; f[5] = hi.y; f[6] = hi.z; f[7] = hi.w;
    b[tt] = f;
  }

#pragma unroll
  for (int tr = 0; tr < 4; tr++)
#pragma unroll
    for (int tc = 0; tc < 4; tc++)
      acc[tr][tc] = __builtin_amdgcn_mfma_scale_f32_16x16x128_f8f6f4(
          a[tr], b[tc], acc[tr][tc], 0, 0, 0, 0x7f7f7f7f, 0, 0x7f7f7f7f);

  int i_base = i0 + wi, j_base = j0 + wj;
  bool diag_wave = (i_base == j_base);
  bool offdiag_block = (bi != bj);

  float mx = 0.f;
#pragma unroll
  for (int tr = 0; tr < 4; tr++)
#pragma unroll
    for (int tc = 0; tc < 4; tc++)
#pragma unroll
      for (int r = 0; r < 4; r++) {
        float v = acc[tr][tc][r];
        if (diag_wave && tr == tc && lr == quad * 4 + r) v = 0.f;
        mx = fmaxf(mx, fabsf(v));
      }
  if (__any(mx >= 0.9746f)) {
    for (int tr = 0; tr < 4; tr++)
      for (int tc = 0; tc < 4; tc++)
        for (int r = 0; r < 4; r++) {
          float v = acc[tr][tc][r];
          int row = i_base + tr * 16 + quad * 4 + r;
          int col = j_base + tc * 16 + lr;
          if (v * v >= 0.95f && row != col) {
            atomicAdd(&cnt[row], 1);
            if (offdiag_block) atomicAdd(&cnt[col], 1);
          }
        }
  }
}

// ---- fused MLP: 32 rows/block, barrier-free k-loops, SW-pipelined B loads -
// LDS: Ahs [32][200] | Als [32][200] | H1 packed [32][256] = 58368B.
// B fragments prefetched distance-1 from pre-split global W planes; kc=0
// fragments prefetched ACROSS the preceding barrier.
__global__ __launch_bounds__(256) void fused_mlp_kernel(const float* __restrict__ x,
                                                        const float* __restrict__ q,
                                                        const u16* __restrict__ W1h,
                                                        const u16* __restrict__ W1l,
                                                        const u16* __restrict__ W2h,
                                                        const u16* __restrict__ W2l,
                                                        const float* __restrict__ W1g,
                                                        const float* __restrict__ b1,
                                                        const float* __restrict__ b2,
                                                        const float* __restrict__ W3,
                                                        const float* __restrict__ b3,
                                                        const int* __restrict__ cnt,
                                                        float* __restrict__ out) {
  __shared__ __align__(16) char smem[58368];
  short* Ahs = (short*)smem;                 // [32][APITCH] hi
  short* Als = (short*)(smem + 12800);       // [32][APITCH] lo
  uint*  H1  = (uint*)(smem + 25600);        // [32][256] packed, swizzled
  float* part = (float*)smem;                // [4][32], overlays Ahs at end

  int tid = threadIdx.x;
  int lane = tid & 63;
  int wv = tid >> 6;
  int lr = lane & 15;
  int quad = lane >> 4;
  int mb = blockIdx.x * 32;

  // ---- hoisted scalar/param loads (issue early, consumed late) ----
  float bv1[4], bv2[4], w3v[4], w1gv[4];
#pragma unroll
  for (int tc = 0; tc < 4; ++tc) {
    int n = wv * 64 + tc * 16 + lr;
    bv1[tc] = b1[n];
    bv2[tc] = b2[n];
    w3v[tc] = W3[n];
    w1gv[tc] = W1g[n];
  }
  float gv[2][4];
#pragma unroll
  for (int tt = 0; tt < 2; ++tt)
#pragma unroll
    for (int r = 0; r < 4; ++r)
      gv[tt][r] = (float)cnt[mb + tt * 16 + quad * 4 + r] * (1.0f / 8192.0f);

  // ---- prefetch W1 kc=0 fragments (lands during A-stage + barrier) ----
  size_t base1 = (size_t)(wv * 64 + lr) * K1 + quad * 8;
  bf16x8 pw1h[4], pw1l[4];
#pragma unroll
  for (int tc = 0; tc < 4; ++tc) {
    pw1h[tc] = *(const bf16x8*)(W1h + base1 + (size_t)tc * 16 * K1);
    pw1l[tc] = *(const bf16x8*)(W1l + base1 + (size_t)tc * 16 * K1);
  }

  // ---- A stage: feats[32][192] hi/lo from x, q ----
  {
    int r = tid >> 3;
    int c8 = (tid & 7) * 4;
#pragma unroll
    for (int it = 0; it < 6; ++it) {
      int col = it * 32 + c8;
      float4 v;
      if (it < 4) v = *(const float4*)(x + (size_t)(mb + r) * F_DIM + col);
      else        v = *(const float4*)(q + (size_t)(mb + r) * Q_DIM + (col - 128));
      unsigned short h0, l0, h1, l1, h2, l2, h3, l3;
      split_hl(v.x, h0, l0); split_hl(v.y, h1, l1);
      split_hl(v.z, h2, l2); split_hl(v.w, h3, l3);
      *(uint2*)&Ahs[r * APITCH + col] = (uint2){(uint)h0 | ((uint)h1 << 16), (uint)h2 | ((uint)h3 << 16)};
      *(uint2*)&Als[r * APITCH + col] = (uint2){(uint)l0 | ((uint)l1 << 16), (uint)l2 | ((uint)l3 << 16)};
    }
  }
  __syncthreads();

  f32x4 acc[2][4];
#pragma unroll
  for (int i = 0; i < 2; i++)
#pragma unroll
    for (int j = 0; j < 4; j++) acc[i][j] = (f32x4){0.f, 0.f, 0.f, 0.f};

  // ---- phase 1: h1_pre = feats @ W1^T, K = 192, prefetch distance 1 ----
#pragma unroll
  for (int kc = 0; kc < 6; ++kc) {
    int k0 = kc * 32;
    bf16x8 nw1h[4], nw1l[4];
    if (kc < 5) {
#pragma unroll
      for (int tc = 0; tc < 4; ++tc) {
        nw1h[tc] = *(const bf16x8*)(W1h + base1 + (size_t)tc * 16 * K1 + (kc + 1) * 32);
        nw1l[tc] = *(const bf16x8*)(W1l + base1 + (size_t)tc * 16 * K1 + (kc + 1) * 32);
      }
    }
    bf16x8 ah[2], al[2];
#pragma unroll
    for (int tt = 0; tt < 2; ++tt) {
      int row = tt * 16 + lr;
      ah[tt] = *(const bf16x8*)&Ahs[row * APITCH + k0 + quad * 8];
      al[tt] = *(const bf16x8*)&Als[row * APITCH + k0 + quad * 8];
    }
#pragma unroll
    for (int tt = 0; tt < 2; ++tt)
#pragma unroll
      for (int tc = 0; tc < 4; ++tc) {
        acc[tt][tc] = __builtin_amdgcn_mfma_f32_16x16x32_bf16(ah[tt], pw1h[tc], acc[tt][tc], 0, 0, 0);
        acc[tt][tc] = __builtin_amdgcn_mfma_f32_16x16x32_bf16(ah[tt], pw1l[tc], acc[tt][tc], 0, 0, 0);
        acc[tt][tc] = __builtin_amdgcn_mfma_f32_16x16x32_bf16(al[tt], pw1h[tc], acc[tt][tc], 0, 0, 0);
      }
    if (kc < 5) {
#pragma unroll
      for (int tc = 0; tc < 4; ++tc) { pw1h[tc] = nw1h[tc]; pw1l[tc] = nw1l[tc]; }
    }
  }

  // ---- prefetch W2 kc=0 fragments (lands during epilogue + barrier) ----
  size_t base2 = (size_t)(wv * 64 + lr) * 256 + quad * 8;
  bf16x8 pw2h[4], pw2l[4];
#pragma unroll
  for (int tc = 0; tc < 4; ++tc) {
    pw2h[tc] = *(const bf16x8*)(W2h + base2 + (size_t)tc * 16 * 256);
    pw2l[tc] = *(const bf16x8*)(W2l + base2 + (size_t)tc * 16 * 256);
  }

  // ---- graph-feature column: exact fp32 rank-1 update ----
#pragma unroll
  for (int tc = 0; tc < 4; ++tc) {
    float w = w1gv[tc];
#pragma unroll
    for (int tt = 0; tt < 2; ++tt)
#pragma unroll
      for (int r = 0; r < 4; ++r)
        acc[tt][tc][r] += gv[tt][r] * w;
  }

  // ---- phase-1 epilogue: relu+bias -> H1 (packed, swizzled) ----
#pragma unroll
  for (int tc = 0; tc < 4; ++tc) {
    int n = wv * 64 + tc * 16 + lr;
    float bv = bv1[tc];
    int g = n >> 2, jj = n & 3;
#pragma unroll
    for (int tt = 0; tt < 2; ++tt)
#pragma unroll
      for (int r = 0; r < 4; ++r) {
        int row = tt * 16 + quad * 4 + r;
        float v = fmaxf(acc[tt][tc][r] + bv, 0.f);
        H1[row * 256 + ((g ^ (row & 31)) * 4 + jj)] = packhl(v);
      }
  }
#pragma unroll
  for (int i = 0; i < 2; i++)
#pragma unroll
    for (int j = 0; j < 4; j++) acc[i][j] = (f32x4){0.f, 0.f, 0.f, 0.f};
  __syncthreads();   // all H1 writes visible before phase 2 reads

  // ---- phase 2: h2 = relu(h1 @ W2^T + b2), K = 256, prefetch distance 1 ----
#pragma unroll
  for (int kc = 0; kc < 8; ++kc) {
    bf16x8 nw2h[4], nw2l[4];
    if (kc < 7) {
#pragma unroll
      for (int tc = 0; tc < 4; ++tc) {
        nw2h[tc] = *(const bf16x8*)(W2h + base2 + (size_t)tc * 16 * 256 + (kc + 1) * 32);
        nw2l[tc] = *(const bf16x8*)(W2l + base2 + (size_t)tc * 16 * 256 + (kc + 1) * 32);
      }
    }
    bf16x8 ah[2], al[2];
#pragma unroll
    for (int tt = 0; tt < 2; ++tt) {
      int row = tt * 16 + lr;
      int cb = kc * 8 + quad * 2;
      uint4 u0 = *(const uint4*)&H1[row * 256 + ((cb ^ (row & 31)) * 4)];
      uint4 u1 = *(const uint4*)&H1[row * 256 + (((cb + 1) ^ (row & 31)) * 4)];
      uu h, l;
      h.u.x = (u0.x & 0xffffu) | (u0.y << 16);
      h.u.y = (u0.z & 0xffffu) | (u0.w << 16);
      h.u.z = (u1.x & 0xffffu) | (u1.y << 16);
      h.u.w = (u1.z & 0xffffu) | (u1.w << 16);
      l.u.x = (u0.x >> 16) | (u0.y & 0xffff0000u);
      l.u.y = (u0.z >> 16) | (u0.w & 0xffff0000u);
      l.u.z = (u1.x >> 16) | (u1.y & 0xffff0000u);
      l.u.w = (u1.z >> 16) | (u1.w & 0xffff0000u);
      ah[tt] = h.v; al[tt] = l.v;
    }
#pragma unroll
    for (int tt = 0; tt < 2; ++tt)
#pragma unroll
      for (int tc = 0; tc < 4; ++tc) {
        acc[tt][tc] = __builtin_amdgcn_mfma_f32_16x16x32_bf16(ah[tt], pw2h[tc], acc[tt][tc], 0, 0, 0);
        acc[tt][tc] = __builtin_amdgcn_mfma_f32_16x16x32_bf16(ah[tt], pw2l[tc], acc[tt][tc], 0, 0, 0);
        acc[tt][tc] = __builtin_amdgcn_mfma_f32_16x16x32_bf16(al[tt], pw2h[tc], acc[tt][tc], 0, 0, 0);
      }
    if (kc < 7) {
#pragma unroll
      for (int tc = 0; tc < 4; ++tc) { pw2h[tc] = nw2h[tc]; pw2l[tc] = nw2l[tc]; }
    }
  }

  // ---- phase-2 epilogue: relu+bias, dot W3, cross-wave reduce, store ----
  float s[2][4];
#pragma unroll
  for (int tt = 0; tt < 2; ++tt)
#pragma unroll
    for (int r = 0; r < 4; ++r) s[tt][r] = 0.f;
#pragma unroll
  for (int tc = 0; tc < 4; ++tc) {
    float bv = bv2[tc];
    float w3 = w3v[tc];
#pragma unroll
    for (int tt = 0; tt < 2; ++tt)
#pragma unroll
      for (int r = 0; r < 4; ++r)
        s[tt][r] += fmaxf(acc[tt][tc][r] + bv, 0.f) * w3;
  }
#pragma unroll
  for (int tt = 0; tt < 2; ++tt)
#pragma unroll
    for (int r = 0; r < 4; ++r) {
      s[tt][r] += __shfl_xor(s[tt][r], 1);
      s[tt][r] += __shfl_xor(s[tt][r], 2);
      s[tt][r] += __shfl_xor(s[tt][r], 4);
      s[tt][r] += __shfl_xor(s[tt][r], 8);
    }
  // part overlays Ahs: all A reads completed before the post-H1 barrier
  if (lr == 0) {
#pragma unroll
    for (int tt = 0; tt < 2; ++tt)
#pragma unroll
      for (int r = 0; r < 4; ++r)
        part[wv * 32 + tt * 16 + quad * 4 + r] = s[tt][r];
  }
  __syncthreads();
  if (tid < 32)
    out[mb + tid] = part[tid] + part[32 + tid] + part[64 + tid] + part[96 + tid] + b3[0];
}

extern "C" void kernel_launch(void* const* d_in, const int* in_sizes, int n_in,
                              void* d_out, int out_size, void* d_ws, size_t ws_size,
                              hipStream_t stream) {
  const float* x  = (const float*)d_in[0];
  const float* q  = (const float*)d_in[1];
  const float* W1 = (const float*)d_in[2];
  const float* b1 = (const float*)d_in[3];
  const float* W2 = (const float*)d_in[4];
  const float* b2 = (const float*)d_in[5];
  const float* W3 = (const float*)d_in[6];
  const float* b3 = (const float*)d_in[7];
  float* out = (float*)d_out;

  char* ws = (char*)d_ws;
  unsigned char* xn8 = (unsigned char*)(ws);         // 1 MB
  int*   cnt = (int*)(ws + 0x100000);                // 32 KB
  u16*   W1h = (u16*)(ws + 0x110000);                // 96 KB  (256 x 192)
  u16*   W1l = (u16*)(ws + 0x128000);                // 96 KB
  u16*   W2h = (u16*)(ws + 0x140000);                // 128 KB (256 x 256)
  u16*   W2l = (u16*)(ws + 0x160000);                // 128 KB
  float* W1g = (float*)(ws + 0x180000);              // 1 KB (W1 col 192, fp32)

  norm_prep_kernel<<<dim3(2048), dim3(256), 0, stream>>>(x, xn8, cnt);
  gram8_kernel<<<dim3(2592), dim3(256), 0, stream>>>(xn8, cnt, W1, W2, W1h, W1l, W2h, W2l, W1g);
  fused_mlp_kernel<<<dim3(256), dim3(256), 0, stream>>>(x, q, W1h, W1l, W2h, W2l, W1g, b1, b2, W3, b3, cnt, out);
}